// Round 5
// baseline (157.115 us; speedup 1.0000x reference)
//
#include <hip/hip_runtime.h>
#include <hip/hip_bf16.h>
#include <math.h>

#define LQ    32
#define LD    512
#define DIM   128
#define NK    21
#define VOCAB 50000

typedef __attribute__((ext_vector_type(8))) short short8;
typedef __attribute__((ext_vector_type(4))) float f32x4;
typedef __attribute__((ext_vector_type(2))) float f32x2;

__device__ __forceinline__ unsigned pkbf(float a, float b) {
    unsigned short ua = __bfloat16_as_ushort(__float2bfloat16(a));
    unsigned short ub = __bfloat16_as_ushort(__float2bfloat16(b));
    return (unsigned)ua | ((unsigned)ub << 16);
}

// ---- prep: pre-normalized bf16 embedding table (one wave per row)
__global__ __launch_bounds__(256, 8)
void knrm_prep(const float* __restrict__ emb, unsigned* __restrict__ emb16) {
    int row  = blockIdx.x * 4 + (threadIdx.x >> 6);
    int lane = threadIdx.x & 63;
    if (row >= VOCAB) return;
    float2 v = ((const float2*)(emb + (size_t)row * DIM))[lane];
    float ss = v.x * v.x + v.y * v.y;
    #pragma unroll
    for (int s = 1; s < 64; s <<= 1) ss += __shfl_xor(ss, s, 64);
    float rn = 1.0f / fmaxf(sqrtf(ss), 1e-12f);
    emb16[(size_t)row * 64 + lane] = pkbf(v.x * rn, v.y * rn);
}

// one block per (b, side); wave w owns doc rows [w*128, w*128+128) x all 32 q.
// __launch_bounds__(256,8): 8 waves/EU -> 8 blocks/CU resident (entire 2048-block
// grid fits the chip at once). VGPR budget 512/8 = 64 — matches the natural
// allocation of this kernel (R3 measured VGPR_Count=64 unforced).
__global__ __launch_bounds__(256, 8)
void knrm_main(const unsigned short* __restrict__ emb16,
               const float* __restrict__ w0, const float* __restrict__ b0,
               const float* __restrict__ w1, const float* __restrict__ b1,
               const float* __restrict__ w2, const float* __restrict__ b2,
               const int* __restrict__ q1, const int* __restrict__ d1,
               const int* __restrict__ q2, const int* __restrict__ d2,
               float* __restrict__ logits)
{
    __shared__ __align__(16) char smem[16320];
    unsigned short (*Bq)[DIM] = (unsigned short(*)[DIM])(smem);     // [0,8192)
    float (*SSh)[LQ][20] = (float(*)[LQ][20])(smem);                // alias [0,10240)
    int*   dtokS = (int*)(smem + 10240);                            // [10240,12288)
    float (*SSe)[LQ] = (float(*)[LQ])(smem + 12288);                // [12288,13312)
    int*   qtokS = (int*)(smem + 13312);
    float* Lbuf  = (float*)(smem + 13440);                          // 672 floats
    float* xk    = (float*)(smem + 16128);
    float* h0s   = (float*)(smem + 16224);
    float* h1s   = (float*)(smem + 16264);

    const int bid  = blockIdx.x;
    const int b    = bid >> 1;
    const int side = bid & 1;
    const int tid  = threadIdx.x;
    const int w    = tid >> 6;
    const int lane = tid & 63;
    const int rg   = lane >> 4;       // k-subgroup / C row-group
    const int l15  = lane & 15;

    const int* qt = (side ? q2 : q1) + b * LQ;
    const int* dt = (side ? d2 : d1) + b * LD;

    if (tid < LQ) qtokS[tid] = qt[tid];
    dtokS[tid]       = dt[tid];
    dtokS[tid + 256] = dt[tid + 256];
    __syncthreads();   // barrier 0: token tables resident

    // ---- stage normalized q rows (bf16) into LDS via async DMA, swizzled source.
    //      NOTE: no other VMEM ops are issued inside this window (DMA issue ->
    //      barrier 1) — mixing plain loads into the vmcnt queue here allowed a
    //      counted (non-zero) drain before the barrier and raced in R2.
    {
        #pragma unroll
        for (int cc = 0; cc < 2; ++cc) {
            int rloc = cc * 4 + rg;                 // row within wave's 8
            int tok  = qtokS[w * 8 + rloc];
            int sw   = (rloc & 7) << 3;
            int col  = (l15 * 8) ^ sw;
            const unsigned short* src = emb16 + (size_t)tok * DIM + col;
            __builtin_amdgcn_global_load_lds(src, &Bq[w * 8 + cc * 4][0], 16, 0, 0);
        }
    }

    // ---- exact-match bin via integer token equality (token 0 = padding excluded)
    {
        int q = tid & 31, g = tid >> 5;
        int qv = qtokS[q];
        int c = 0;
        const int4* dp = (const int4*)&dtokS[g * 64];
        #pragma unroll
        for (int j = 0; j < 16; ++j) {
            int4 dv = dp[j];
            c += (dv.x == qv) + (dv.y == qv) + (dv.z == qv) + (dv.w == qv);
        }
        SSe[g][q] = (qv == 0) ? 0.0f : (float)c;
    }
    __syncthreads();   // barrier 1: Bq resident (vmcnt fully drained)

    // ---- t=0 A-tile gather issued here: latency hides under the bq ds_reads
    //      and barrier 2 below. DMA queue is empty at this point.
    const int dbase = w * 128;
    int tok0 = dtokS[dbase + l15];
    const unsigned short* ap0 = emb16 + (size_t)tok0 * DIM + rg * 8;
    short8 a0 = *(const short8*)(ap0);
    short8 a1 = *(const short8*)(ap0 + 32);
    short8 a2 = *(const short8*)(ap0 + 64);
    short8 a3 = *(const short8*)(ap0 + 96);

    // ---- hoist both q-half B-fragments to registers
    const int swB = (l15 & 7) << 3;   // rows l15 and l15+16 share (row&7)
    short8 bq0[4], bq1[4];
    #pragma unroll
    for (int g = 0; g < 4; ++g) {
        bq0[g] = *(const short8*)&Bq[l15][(g * 32 + rg * 8) ^ swB];
        bq1[g] = *(const short8*)&Bq[l15 + 16][(g * 32 + rg * 8) ^ swB];
    }
    __syncthreads();   // barrier 2: all waves done reading Bq before SSh overwrite

    // packed-f32 accumulators: .x = c0 tile (rows l15), .y = c1 tile (rows l15+16)
    f32x2 accP[10], accM[10];
    #pragma unroll
    for (int j = 0; j < 10; ++j) {
        accP[j] = (f32x2){0.0f, 0.0f};
        accM[j] = (f32x2){0.0f, 0.0f};
    }

    // packed chain: two matrix elements per instruction via v_pk_*_f32.
    auto chain2 = [&](f32x2 x, f32x2* AP, f32x2* AM) {
        f32x2 t1 = x * -72.134752f + 7.2134752f;      // pk_fma
        f32x2 Ea = t1 * x + -0.18033688f;             // pk_fma
        f32x2 Ra = x * 14.4269504f + -0.7213475f;     // pk_fma
        f32x2 E, R, rc;
        E.x = __builtin_amdgcn_exp2f(Ea.x);
        E.y = __builtin_amdgcn_exp2f(Ea.y);
        R.x = __builtin_amdgcn_exp2f(Ra.x);
        R.y = __builtin_amdgcn_exp2f(Ra.y);
        rc.x = __builtin_amdgcn_rcpf(R.x);
        rc.y = __builtin_amdgcn_rcpf(R.y);
        f32x2 tP = E;
        f32x2 tM = E * rc;
        AP[0] += tP; AM[0] += tM;
        #pragma unroll
        for (int j = 1; j < 10; ++j) {
            tP *= R; tM *= rc;
            AP[j] += tP; AM[j] += tM;
        }
    };

    // ---- 8 doc tiles of 16 rows per wave, software-pipelined:
    //      issue tile t+1's gather after tile t's MFMAs; chains cover the latency.
    //      Pure register dataflow — no LDS writes, no race surface.
    #pragma unroll 1
    for (int t = 0; t < 8; ++t) {
        f32x4 c0 = {0, 0, 0, 0}, c1 = {0, 0, 0, 0};
        c0 = __builtin_amdgcn_mfma_f32_16x16x32_bf16(a0, bq0[0], c0, 0, 0, 0);
        c1 = __builtin_amdgcn_mfma_f32_16x16x32_bf16(a0, bq1[0], c1, 0, 0, 0);
        c0 = __builtin_amdgcn_mfma_f32_16x16x32_bf16(a1, bq0[1], c0, 0, 0, 0);
        c1 = __builtin_amdgcn_mfma_f32_16x16x32_bf16(a1, bq1[1], c1, 0, 0, 0);
        c0 = __builtin_amdgcn_mfma_f32_16x16x32_bf16(a2, bq0[2], c0, 0, 0, 0);
        c1 = __builtin_amdgcn_mfma_f32_16x16x32_bf16(a2, bq1[2], c1, 0, 0, 0);
        c0 = __builtin_amdgcn_mfma_f32_16x16x32_bf16(a3, bq0[3], c0, 0, 0, 0);
        c1 = __builtin_amdgcn_mfma_f32_16x16x32_bf16(a3, bq1[3], c1, 0, 0, 0);

        // prefetch next tile (t=7 re-touches tile 7: L1-hot, branch-free)
        int nt = (t < 7) ? (t + 1) : 7;
        int ntok = dtokS[dbase + nt * 16 + l15];
        const unsigned short* np = emb16 + (size_t)ntok * DIM + rg * 8;
        short8 n0 = *(const short8*)(np);
        short8 n1 = *(const short8*)(np + 32);
        short8 n2 = *(const short8*)(np + 64);
        short8 n3 = *(const short8*)(np + 96);

        #pragma unroll
        for (int r = 0; r < 4; ++r) {
            f32x2 x;
            x.x = c0[r];
            x.y = c1[r];
            chain2(x, accP, accM);
        }

        a0 = n0; a1 = n1; a2 = n2; a3 = n3;
    }

    // ---- reduce over the 4 row-groups (same l15, different rg)
    #pragma unroll
    for (int j = 0; j < 10; ++j) {
        accP[j].x += __shfl_xor(accP[j].x, 16, 64); accP[j].x += __shfl_xor(accP[j].x, 32, 64);
        accP[j].y += __shfl_xor(accP[j].y, 16, 64); accP[j].y += __shfl_xor(accP[j].y, 32, 64);
        accM[j].x += __shfl_xor(accM[j].x, 16, 64); accM[j].x += __shfl_xor(accM[j].x, 32, 64);
        accM[j].y += __shfl_xor(accM[j].y, 16, 64); accM[j].y += __shfl_xor(accM[j].y, 32, 64);
    }
    if (lane < 16) {
        const float GP[10] = {1.0f, 0.60653066f, 0.13533528f, 0.011108997f,
                              3.3546263e-4f, 3.7266532e-6f, 1.5229979e-8f,
                              2.2897348e-11f, 1.2664166e-14f, 2.5767430e-18f};
        const float GM[10] = {0.60653066f, 0.13533528f, 0.011108997f,
                              3.3546263e-4f, 3.7266532e-6f, 1.5229979e-8f,
                              2.2897348e-11f, 1.2664166e-14f, 2.5767430e-18f,
                              1.9287498e-22f};
        #pragma unroll
        for (int j = 0; j < 10; ++j) {
            SSh[w][l15][10 + j]      = accP[j].x * GP[j];
            SSh[w][l15][9 - j]       = accM[j].x * GM[j];
            SSh[w][l15 + 16][10 + j] = accP[j].y * GP[j];
            SSh[w][l15 + 16][9 - j]  = accM[j].y * GM[j];
        }
    }
    __syncthreads();

    // ---- log1p over [q][k]
    for (int idx = tid; idx < LQ * NK; idx += 256) {
        int q = idx / NK, k = idx - q * NK;
        float s;
        if (k == 20) {
            s = SSe[0][q] + SSe[1][q] + SSe[2][q] + SSe[3][q]
              + SSe[4][q] + SSe[5][q] + SSe[6][q] + SSe[7][q];
        } else {
            s = SSh[0][q][k] + SSh[1][q][k] + SSh[2][q][k] + SSh[3][q][k];
        }
        Lbuf[idx] = log1pf(s);
    }
    __syncthreads();

    // ---- pool over q -> 21 features
    if (tid < NK) {
        float s = 0.0f;
        #pragma unroll 1
        for (int q = 0; q < LQ; ++q) s += Lbuf[q * NK + tid];
        xk[tid] = s;
    }
    __syncthreads();

    // ---- MLP 21 -> 10 -> 5 -> 1
    if (tid < 10) {
        float s = b0[tid];
        #pragma unroll
        for (int k = 0; k < NK; ++k) s = fmaf(xk[k], w0[tid * NK + k], s);
        h0s[tid] = fmaxf(s, 0.0f);
    }
    __syncthreads();
    if (tid < 5) {
        float s = b1[tid];
        #pragma unroll
        for (int k = 0; k < 10; ++k) s = fmaf(h0s[k], w1[tid * 10 + k], s);
        h1s[tid] = fmaxf(s, 0.0f);
    }
    __syncthreads();
    if (tid == 0) {
        float s = b2[0];
        #pragma unroll
        for (int k = 0; k < 5; ++k) s = fmaf(h1s[k], w2[k], s);
        logits[bid] = s;
    }
}

__global__ void knrm_fin(const float* __restrict__ lg, float* __restrict__ out) {
    int i = blockIdx.x * 256 + threadIdx.x;
    if (i < 1024) {
        float z = lg[2 * i] - lg[2 * i + 1];
        out[i] = 1.0f / (1.0f + __expf(-z));
    }
}

extern "C" void kernel_launch(void* const* d_in, const int* in_sizes, int n_in,
                              void* d_out, int out_size, void* d_ws, size_t ws_size,
                              hipStream_t stream) {
    const float* emb = (const float*)d_in[0];
    const float* w0  = (const float*)d_in[1];
    const float* b0  = (const float*)d_in[2];
    const float* w1  = (const float*)d_in[3];
    const float* b1  = (const float*)d_in[4];
    const float* w2  = (const float*)d_in[5];
    const float* b2  = (const float*)d_in[6];
    const int*   q1  = (const int*)d_in[7];
    const int*   d1  = (const int*)d_in[8];
    const int*   q2  = (const int*)d_in[9];
    const int*   d2  = (const int*)d_in[10];
    float* out = (float*)d_out;

    unsigned* emb16 = (unsigned*)d_ws;                        // 12.8 MB
    float* logits   = (float*)((char*)d_ws + 12800000);       // +8 KB

    knrm_prep<<<(VOCAB + 3) / 4, 256, 0, stream>>>(emb, emb16);
    knrm_main<<<2048, 256, 0, stream>>>((const unsigned short*)emb16,
                                        w0, b0, w1, b1, w2, b2,
                                        q1, d1, q2, d2, logits);
    knrm_fin<<<4, 256, 0, stream>>>(logits, out);
}

// Round 6
// 121.847 us; speedup vs baseline: 1.2895x; 1.2895x over previous
//
#include <hip/hip_runtime.h>
#include <hip/hip_bf16.h>
#include <math.h>

#define LQ    32
#define LD    512
#define DIM   128
#define NK    21
#define VOCAB 50000

typedef __attribute__((ext_vector_type(8))) short short8;
typedef __attribute__((ext_vector_type(4))) float f32x4;
typedef __attribute__((ext_vector_type(2))) float f32x2;

__device__ __forceinline__ unsigned pkbf(float a, float b) {
    unsigned short ua = __bfloat16_as_ushort(__float2bfloat16(a));
    unsigned short ub = __bfloat16_as_ushort(__float2bfloat16(b));
    return (unsigned)ua | ((unsigned)ub << 16);
}

// ---- prep: pre-normalized bf16 embedding table (one wave per row)
__global__ __launch_bounds__(256, 8)
void knrm_prep(const float* __restrict__ emb, unsigned* __restrict__ emb16) {
    int row  = blockIdx.x * 4 + (threadIdx.x >> 6);
    int lane = threadIdx.x & 63;
    if (row >= VOCAB) return;
    float2 v = ((const float2*)(emb + (size_t)row * DIM))[lane];
    float ss = v.x * v.x + v.y * v.y;
    #pragma unroll
    for (int s = 1; s < 64; s <<= 1) ss += __shfl_xor(ss, s, 64);
    float rn = 1.0f / fmaxf(sqrtf(ss), 1e-12f);
    emb16[(size_t)row * 64 + lane] = pkbf(v.x * rn, v.y * rn);
}

// one block per (b, side); wave w owns doc rows [w*128, w*128+128) x all 32 q.
// __launch_bounds__(256,6): VGPR cap ~85 > natural 64 (R3) so codegen unchanged,
// but residency rises 4 -> 6 blocks/CU. (256,8) forced cap=64 and the allocator
// fell off a cliff: VGPR=32 + ~430MB/dispatch scratch spill (R5). Do not cap at
// exactly the natural allocation.
__global__ __launch_bounds__(256, 6)
void knrm_main(const unsigned short* __restrict__ emb16,
               const float* __restrict__ w0, const float* __restrict__ b0,
               const float* __restrict__ w1, const float* __restrict__ b1,
               const float* __restrict__ w2, const float* __restrict__ b2,
               const int* __restrict__ q1, const int* __restrict__ d1,
               const int* __restrict__ q2, const int* __restrict__ d2,
               float* __restrict__ logits)
{
    __shared__ __align__(16) char smem[16320];
    unsigned short (*Bq)[DIM] = (unsigned short(*)[DIM])(smem);     // [0,8192)
    float (*SSh)[LQ][20] = (float(*)[LQ][20])(smem);                // alias [0,10240)
    int*   dtokS = (int*)(smem + 10240);                            // [10240,12288)
    float (*SSe)[LQ] = (float(*)[LQ])(smem + 12288);                // [12288,13312)
    int*   qtokS = (int*)(smem + 13312);
    float* Lbuf  = (float*)(smem + 13440);                          // 672 floats
    float* xk    = (float*)(smem + 16128);
    float* h0s   = (float*)(smem + 16224);
    float* h1s   = (float*)(smem + 16264);

    const int bid  = blockIdx.x;
    const int b    = bid >> 1;
    const int side = bid & 1;
    const int tid  = threadIdx.x;
    const int w    = tid >> 6;
    const int lane = tid & 63;
    const int rg   = lane >> 4;       // k-subgroup / C row-group
    const int l15  = lane & 15;

    const int* qt = (side ? q2 : q1) + b * LQ;
    const int* dt = (side ? d2 : d1) + b * LD;

    if (tid < LQ) qtokS[tid] = qt[tid];
    dtokS[tid]       = dt[tid];
    dtokS[tid + 256] = dt[tid + 256];
    __syncthreads();   // barrier 0: token tables resident

    // ---- stage normalized q rows (bf16) into LDS via async DMA, swizzled source.
    //      NOTE: no other VMEM ops are issued inside this window (DMA issue ->
    //      barrier 1) — mixing plain loads into the vmcnt queue here allowed a
    //      counted (non-zero) drain before the barrier and raced in R2.
    {
        #pragma unroll
        for (int cc = 0; cc < 2; ++cc) {
            int rloc = cc * 4 + rg;                 // row within wave's 8
            int tok  = qtokS[w * 8 + rloc];
            int sw   = (rloc & 7) << 3;
            int col  = (l15 * 8) ^ sw;
            const unsigned short* src = emb16 + (size_t)tok * DIM + col;
            __builtin_amdgcn_global_load_lds(src, &Bq[w * 8 + cc * 4][0], 16, 0, 0);
        }
    }

    // ---- exact-match bin via integer token equality (token 0 = padding excluded)
    {
        int q = tid & 31, g = tid >> 5;
        int qv = qtokS[q];
        int c = 0;
        const int4* dp = (const int4*)&dtokS[g * 64];
        #pragma unroll
        for (int j = 0; j < 16; ++j) {
            int4 dv = dp[j];
            c += (dv.x == qv) + (dv.y == qv) + (dv.z == qv) + (dv.w == qv);
        }
        SSe[g][q] = (qv == 0) ? 0.0f : (float)c;
    }
    __syncthreads();   // barrier 1: Bq resident (vmcnt fully drained)

    // ---- t=0 A-tile gather issued here: latency hides under the bq ds_reads
    //      and barrier 2 below. DMA queue is empty at this point.
    const int dbase = w * 128;
    int tok0 = dtokS[dbase + l15];
    const unsigned short* ap0 = emb16 + (size_t)tok0 * DIM + rg * 8;
    short8 a0 = *(const short8*)(ap0);
    short8 a1 = *(const short8*)(ap0 + 32);
    short8 a2 = *(const short8*)(ap0 + 64);
    short8 a3 = *(const short8*)(ap0 + 96);

    // ---- hoist both q-half B-fragments to registers
    const int swB = (l15 & 7) << 3;   // rows l15 and l15+16 share (row&7)
    short8 bq0[4], bq1[4];
    #pragma unroll
    for (int g = 0; g < 4; ++g) {
        bq0[g] = *(const short8*)&Bq[l15][(g * 32 + rg * 8) ^ swB];
        bq1[g] = *(const short8*)&Bq[l15 + 16][(g * 32 + rg * 8) ^ swB];
    }
    __syncthreads();   // barrier 2: all waves done reading Bq before SSh overwrite

    // packed-f32 accumulators: .x = c0 tile (rows l15), .y = c1 tile (rows l15+16)
    f32x2 accP[10], accM[10];
    #pragma unroll
    for (int j = 0; j < 10; ++j) {
        accP[j] = (f32x2){0.0f, 0.0f};
        accM[j] = (f32x2){0.0f, 0.0f};
    }

    // packed chain: two matrix elements per instruction via v_pk_*_f32.
    auto chain2 = [&](f32x2 x, f32x2* AP, f32x2* AM) {
        f32x2 t1 = x * -72.134752f + 7.2134752f;      // pk_fma
        f32x2 Ea = t1 * x + -0.18033688f;             // pk_fma
        f32x2 Ra = x * 14.4269504f + -0.7213475f;     // pk_fma
        f32x2 E, R, rc;
        E.x = __builtin_amdgcn_exp2f(Ea.x);
        E.y = __builtin_amdgcn_exp2f(Ea.y);
        R.x = __builtin_amdgcn_exp2f(Ra.x);
        R.y = __builtin_amdgcn_exp2f(Ra.y);
        rc.x = __builtin_amdgcn_rcpf(R.x);
        rc.y = __builtin_amdgcn_rcpf(R.y);
        f32x2 tP = E;
        f32x2 tM = E * rc;
        AP[0] += tP; AM[0] += tM;
        #pragma unroll
        for (int j = 1; j < 10; ++j) {
            tP *= R; tM *= rc;
            AP[j] += tP; AM[j] += tM;
        }
    };

    // ---- 8 doc tiles of 16 rows per wave, software-pipelined:
    //      issue tile t+1's gather after tile t's MFMAs; chains cover the latency.
    //      Pure register dataflow — no LDS writes, no race surface.
    #pragma unroll 1
    for (int t = 0; t < 8; ++t) {
        f32x4 c0 = {0, 0, 0, 0}, c1 = {0, 0, 0, 0};
        c0 = __builtin_amdgcn_mfma_f32_16x16x32_bf16(a0, bq0[0], c0, 0, 0, 0);
        c1 = __builtin_amdgcn_mfma_f32_16x16x32_bf16(a0, bq1[0], c1, 0, 0, 0);
        c0 = __builtin_amdgcn_mfma_f32_16x16x32_bf16(a1, bq0[1], c0, 0, 0, 0);
        c1 = __builtin_amdgcn_mfma_f32_16x16x32_bf16(a1, bq1[1], c1, 0, 0, 0);
        c0 = __builtin_amdgcn_mfma_f32_16x16x32_bf16(a2, bq0[2], c0, 0, 0, 0);
        c1 = __builtin_amdgcn_mfma_f32_16x16x32_bf16(a2, bq1[2], c1, 0, 0, 0);
        c0 = __builtin_amdgcn_mfma_f32_16x16x32_bf16(a3, bq0[3], c0, 0, 0, 0);
        c1 = __builtin_amdgcn_mfma_f32_16x16x32_bf16(a3, bq1[3], c1, 0, 0, 0);

        // prefetch next tile (t=7 re-touches tile 7: L1-hot, branch-free)
        int nt = (t < 7) ? (t + 1) : 7;
        int ntok = dtokS[dbase + nt * 16 + l15];
        const unsigned short* np = emb16 + (size_t)ntok * DIM + rg * 8;
        short8 n0 = *(const short8*)(np);
        short8 n1 = *(const short8*)(np + 32);
        short8 n2 = *(const short8*)(np + 64);
        short8 n3 = *(const short8*)(np + 96);

        #pragma unroll
        for (int r = 0; r < 4; ++r) {
            f32x2 x;
            x.x = c0[r];
            x.y = c1[r];
            chain2(x, accP, accM);
        }

        a0 = n0; a1 = n1; a2 = n2; a3 = n3;
    }

    // ---- reduce over the 4 row-groups (same l15, different rg)
    #pragma unroll
    for (int j = 0; j < 10; ++j) {
        accP[j].x += __shfl_xor(accP[j].x, 16, 64); accP[j].x += __shfl_xor(accP[j].x, 32, 64);
        accP[j].y += __shfl_xor(accP[j].y, 16, 64); accP[j].y += __shfl_xor(accP[j].y, 32, 64);
        accM[j].x += __shfl_xor(accM[j].x, 16, 64); accM[j].x += __shfl_xor(accM[j].x, 32, 64);
        accM[j].y += __shfl_xor(accM[j].y, 16, 64); accM[j].y += __shfl_xor(accM[j].y, 32, 64);
    }
    if (lane < 16) {
        const float GP[10] = {1.0f, 0.60653066f, 0.13533528f, 0.011108997f,
                              3.3546263e-4f, 3.7266532e-6f, 1.5229979e-8f,
                              2.2897348e-11f, 1.2664166e-14f, 2.5767430e-18f};
        const float GM[10] = {0.60653066f, 0.13533528f, 0.011108997f,
                              3.3546263e-4f, 3.7266532e-6f, 1.5229979e-8f,
                              2.2897348e-11f, 1.2664166e-14f, 2.5767430e-18f,
                              1.9287498e-22f};
        #pragma unroll
        for (int j = 0; j < 10; ++j) {
            SSh[w][l15][10 + j]      = accP[j].x * GP[j];
            SSh[w][l15][9 - j]       = accM[j].x * GM[j];
            SSh[w][l15 + 16][10 + j] = accP[j].y * GP[j];
            SSh[w][l15 + 16][9 - j]  = accM[j].y * GM[j];
        }
    }
    __syncthreads();

    // ---- log1p over [q][k]
    for (int idx = tid; idx < LQ * NK; idx += 256) {
        int q = idx / NK, k = idx - q * NK;
        float s;
        if (k == 20) {
            s = SSe[0][q] + SSe[1][q] + SSe[2][q] + SSe[3][q]
              + SSe[4][q] + SSe[5][q] + SSe[6][q] + SSe[7][q];
        } else {
            s = SSh[0][q][k] + SSh[1][q][k] + SSh[2][q][k] + SSh[3][q][k];
        }
        Lbuf[idx] = log1pf(s);
    }
    __syncthreads();

    // ---- pool over q -> 21 features
    if (tid < NK) {
        float s = 0.0f;
        #pragma unroll 1
        for (int q = 0; q < LQ; ++q) s += Lbuf[q * NK + tid];
        xk[tid] = s;
    }
    __syncthreads();

    // ---- MLP 21 -> 10 -> 5 -> 1
    if (tid < 10) {
        float s = b0[tid];
        #pragma unroll
        for (int k = 0; k < NK; ++k) s = fmaf(xk[k], w0[tid * NK + k], s);
        h0s[tid] = fmaxf(s, 0.0f);
    }
    __syncthreads();
    if (tid < 5) {
        float s = b1[tid];
        #pragma unroll
        for (int k = 0; k < 10; ++k) s = fmaf(h0s[k], w1[tid * 10 + k], s);
        h1s[tid] = fmaxf(s, 0.0f);
    }
    __syncthreads();
    if (tid == 0) {
        float s = b2[0];
        #pragma unroll
        for (int k = 0; k < 5; ++k) s = fmaf(h1s[k], w2[k], s);
        logits[bid] = s;
    }
}

__global__ void knrm_fin(const float* __restrict__ lg, float* __restrict__ out) {
    int i = blockIdx.x * 256 + threadIdx.x;
    if (i < 1024) {
        float z = lg[2 * i] - lg[2 * i + 1];
        out[i] = 1.0f / (1.0f + __expf(-z));
    }
}

extern "C" void kernel_launch(void* const* d_in, const int* in_sizes, int n_in,
                              void* d_out, int out_size, void* d_ws, size_t ws_size,
                              hipStream_t stream) {
    const float* emb = (const float*)d_in[0];
    const float* w0  = (const float*)d_in[1];
    const float* b0  = (const float*)d_in[2];
    const float* w1  = (const float*)d_in[3];
    const float* b1  = (const float*)d_in[4];
    const float* w2  = (const float*)d_in[5];
    const float* b2  = (const float*)d_in[6];
    const int*   q1  = (const int*)d_in[7];
    const int*   d1  = (const int*)d_in[8];
    const int*   q2  = (const int*)d_in[9];
    const int*   d2  = (const int*)d_in[10];
    float* out = (float*)d_out;

    unsigned* emb16 = (unsigned*)d_ws;                        // 12.8 MB
    float* logits   = (float*)((char*)d_ws + 12800000);       // +8 KB

    knrm_prep<<<(VOCAB + 3) / 4, 256, 0, stream>>>(emb, emb16);
    knrm_main<<<2048, 256, 0, stream>>>((const unsigned short*)emb16,
                                        w0, b0, w1, b1, w2, b2,
                                        q1, d1, q2, d2, logits);
    knrm_fin<<<4, 256, 0, stream>>>(logits, out);
}

// Round 7
// 65.543 us; speedup vs baseline: 2.3971x; 1.8590x over previous
//
#include <hip/hip_runtime.h>
#include <hip/hip_bf16.h>
#include <math.h>

#define LQ    32
#define LD    512
#define DIM   128
#define NK    21
#define VOCAB 50000

typedef __attribute__((ext_vector_type(8))) short short8;
typedef __attribute__((ext_vector_type(4))) float f32x4;
typedef __attribute__((ext_vector_type(2))) float f32x2;

__device__ __forceinline__ unsigned pkbf(float a, float b) {
    unsigned short ua = __bfloat16_as_ushort(__float2bfloat16(a));
    unsigned short ub = __bfloat16_as_ushort(__float2bfloat16(b));
    return (unsigned)ua | ((unsigned)ub << 16);
}

// ---- prep: pre-normalized bf16 embedding table (one wave per row)
__global__ __launch_bounds__(256, 8)
void knrm_prep(const float* __restrict__ emb, unsigned* __restrict__ emb16) {
    int row  = blockIdx.x * 4 + (threadIdx.x >> 6);
    int lane = threadIdx.x & 63;
    if (row >= VOCAB) return;
    float2 v = ((const float2*)(emb + (size_t)row * DIM))[lane];
    float ss = v.x * v.x + v.y * v.y;
    #pragma unroll
    for (int s = 1; s < 64; s <<= 1) ss += __shfl_xor(ss, s, 64);
    float rn = 1.0f / fmaxf(sqrtf(ss), 1e-12f);
    emb16[(size_t)row * 64 + lane] = pkbf(v.x * rn, v.y * rn);
}

// one block per (b, side); wave w owns doc rows [w*128, w*128+128) x all 32 q.
// __launch_bounds__(256,4): occupancy ceiling for this kernel. gfx950 occupancy
// quanta are coarse (waves halve at vgpr=64/128): (256,8) and (256,6) both forced
// the allocator below the ~64-VGPR live set -> catastrophic scratch spill
// (R5: 430MB, R6: 220MB per dispatch). Do not raise.
__global__ __launch_bounds__(256, 4)
void knrm_main(const unsigned short* __restrict__ emb16,
               const float* __restrict__ w0, const float* __restrict__ b0,
               const float* __restrict__ w1, const float* __restrict__ b1,
               const float* __restrict__ w2, const float* __restrict__ b2,
               const int* __restrict__ q1, const int* __restrict__ d1,
               const int* __restrict__ q2, const int* __restrict__ d2,
               float* __restrict__ logits)
{
    __shared__ __align__(16) char smem[16320];
    unsigned short (*Bq)[DIM] = (unsigned short(*)[DIM])(smem);     // [0,8192)
    float (*SSh)[LQ][20] = (float(*)[LQ][20])(smem);                // alias [0,10240)
    int*   dtokS = (int*)(smem + 10240);                            // [10240,12288)
    float (*SSe)[LQ] = (float(*)[LQ])(smem + 12288);                // [12288,13312)
    int*   qtokS = (int*)(smem + 13312);
    float* Lbuf  = (float*)(smem + 13440);                          // 672 floats
    float* xk    = (float*)(smem + 16128);
    float* h0s   = (float*)(smem + 16224);
    float* h1s   = (float*)(smem + 16264);

    const int bid  = blockIdx.x;
    const int b    = bid >> 1;
    const int side = bid & 1;
    const int tid  = threadIdx.x;
    const int w    = tid >> 6;
    const int lane = tid & 63;
    const int rg   = lane >> 4;       // k-subgroup / C row-group
    const int l15  = lane & 15;

    const int* qt = (side ? q2 : q1) + b * LQ;
    const int* dt = (side ? d2 : d1) + b * LD;

    if (tid < LQ) qtokS[tid] = qt[tid];
    dtokS[tid]       = dt[tid];
    dtokS[tid + 256] = dt[tid + 256];
    __syncthreads();   // barrier 0: token tables resident

    // ---- stage normalized q rows (bf16) into LDS via async DMA, swizzled source.
    //      NOTE: no other VMEM ops are issued inside this window (DMA issue ->
    //      barrier 1) — mixing plain loads into the vmcnt queue here allowed a
    //      counted (non-zero) drain before the barrier and raced in R2.
    {
        #pragma unroll
        for (int cc = 0; cc < 2; ++cc) {
            int rloc = cc * 4 + rg;                 // row within wave's 8
            int tok  = qtokS[w * 8 + rloc];
            int sw   = (rloc & 7) << 3;
            int col  = (l15 * 8) ^ sw;
            const unsigned short* src = emb16 + (size_t)tok * DIM + col;
            __builtin_amdgcn_global_load_lds(src, &Bq[w * 8 + cc * 4][0], 16, 0, 0);
        }
    }

    // ---- exact-match bin via integer token equality (token 0 = padding excluded)
    {
        int q = tid & 31, g = tid >> 5;
        int qv = qtokS[q];
        int c = 0;
        const int4* dp = (const int4*)&dtokS[g * 64];
        #pragma unroll
        for (int j = 0; j < 16; ++j) {
            int4 dv = dp[j];
            c += (dv.x == qv) + (dv.y == qv) + (dv.z == qv) + (dv.w == qv);
        }
        SSe[g][q] = (qv == 0) ? 0.0f : (float)c;
    }
    __syncthreads();   // barrier 1: Bq resident (vmcnt fully drained)

    // ---- t=0 A-tile gather issued here: latency hides under the bq ds_reads
    //      and barrier 2 below. DMA queue is empty at this point.
    const int dbase = w * 128;
    int tok0 = dtokS[dbase + l15];
    const unsigned short* ap0 = emb16 + (size_t)tok0 * DIM + rg * 8;
    short8 a0 = *(const short8*)(ap0);
    short8 a1 = *(const short8*)(ap0 + 32);
    short8 a2 = *(const short8*)(ap0 + 64);
    short8 a3 = *(const short8*)(ap0 + 96);

    // ---- hoist both q-half B-fragments to registers
    const int swB = (l15 & 7) << 3;   // rows l15 and l15+16 share (row&7)
    short8 bq0[4], bq1[4];
    #pragma unroll
    for (int g = 0; g < 4; ++g) {
        bq0[g] = *(const short8*)&Bq[l15][(g * 32 + rg * 8) ^ swB];
        bq1[g] = *(const short8*)&Bq[l15 + 16][(g * 32 + rg * 8) ^ swB];
    }
    __syncthreads();   // barrier 2: all waves done reading Bq before SSh overwrite

    // packed-f32 accumulators: .x = c0 tile (rows l15), .y = c1 tile (rows l15+16)
    f32x2 accP[10], accM[10];
    #pragma unroll
    for (int j = 0; j < 10; ++j) {
        accP[j] = (f32x2){0.0f, 0.0f};
        accM[j] = (f32x2){0.0f, 0.0f};
    }

    // packed chain: two matrix elements per instruction via v_pk_*_f32.
    auto chain2 = [&](f32x2 x, f32x2* AP, f32x2* AM) {
        f32x2 t1 = x * -72.134752f + 7.2134752f;      // pk_fma
        f32x2 Ea = t1 * x + -0.18033688f;             // pk_fma
        f32x2 Ra = x * 14.4269504f + -0.7213475f;     // pk_fma
        f32x2 E, R, rc;
        E.x = __builtin_amdgcn_exp2f(Ea.x);
        E.y = __builtin_amdgcn_exp2f(Ea.y);
        R.x = __builtin_amdgcn_exp2f(Ra.x);
        R.y = __builtin_amdgcn_exp2f(Ra.y);
        rc.x = __builtin_amdgcn_rcpf(R.x);
        rc.y = __builtin_amdgcn_rcpf(R.y);
        f32x2 tP = E;
        f32x2 tM = E * rc;
        AP[0] += tP; AM[0] += tM;
        #pragma unroll
        for (int j = 1; j < 10; ++j) {
            tP *= R; tM *= rc;
            AP[j] += tP; AM[j] += tM;
        }
    };

    // ---- 8 doc tiles of 16 rows per wave, software-pipelined:
    //      issue tile t+1's gather after tile t's MFMAs; chains cover the latency.
    //      Pure register dataflow — no LDS writes, no race surface.
    #pragma unroll 1
    for (int t = 0; t < 8; ++t) {
        f32x4 c0 = {0, 0, 0, 0}, c1 = {0, 0, 0, 0};
        c0 = __builtin_amdgcn_mfma_f32_16x16x32_bf16(a0, bq0[0], c0, 0, 0, 0);
        c1 = __builtin_amdgcn_mfma_f32_16x16x32_bf16(a0, bq1[0], c1, 0, 0, 0);
        c0 = __builtin_amdgcn_mfma_f32_16x16x32_bf16(a1, bq0[1], c0, 0, 0, 0);
        c1 = __builtin_amdgcn_mfma_f32_16x16x32_bf16(a1, bq1[1], c1, 0, 0, 0);
        c0 = __builtin_amdgcn_mfma_f32_16x16x32_bf16(a2, bq0[2], c0, 0, 0, 0);
        c1 = __builtin_amdgcn_mfma_f32_16x16x32_bf16(a2, bq1[2], c1, 0, 0, 0);
        c0 = __builtin_amdgcn_mfma_f32_16x16x32_bf16(a3, bq0[3], c0, 0, 0, 0);
        c1 = __builtin_amdgcn_mfma_f32_16x16x32_bf16(a3, bq1[3], c1, 0, 0, 0);

        // prefetch next tile (t=7 re-touches tile 7: L1-hot, branch-free)
        int nt = (t < 7) ? (t + 1) : 7;
        int ntok = dtokS[dbase + nt * 16 + l15];
        const unsigned short* np = emb16 + (size_t)ntok * DIM + rg * 8;
        short8 n0 = *(const short8*)(np);
        short8 n1 = *(const short8*)(np + 32);
        short8 n2 = *(const short8*)(np + 64);
        short8 n3 = *(const short8*)(np + 96);

        #pragma unroll
        for (int r = 0; r < 4; ++r) {
            f32x2 x;
            x.x = c0[r];
            x.y = c1[r];
            chain2(x, accP, accM);
        }

        // Pin the 40 accumulator floats to ARCH VGPRs. Without this the unified
        // register file allocator parks them in AGPRs (live set ~124 > 64 arch)
        // and every acc update pays v_accvgpr_read/op/v_accvgpr_write (3x issue).
        // bq/a fragments are the correct AGPR residents: MFMA reads AGPRs natively.
        // Zero-instruction hint; once per tile.
        asm volatile("" : "+v"(accP[0]), "+v"(accP[1]), "+v"(accP[2]), "+v"(accP[3]),
                          "+v"(accP[4]), "+v"(accP[5]), "+v"(accP[6]), "+v"(accP[7]),
                          "+v"(accP[8]), "+v"(accP[9]),
                          "+v"(accM[0]), "+v"(accM[1]), "+v"(accM[2]), "+v"(accM[3]),
                          "+v"(accM[4]), "+v"(accM[5]), "+v"(accM[6]), "+v"(accM[7]),
                          "+v"(accM[8]), "+v"(accM[9]));

        a0 = n0; a1 = n1; a2 = n2; a3 = n3;
    }

    // ---- reduce over the 4 row-groups (same l15, different rg)
    #pragma unroll
    for (int j = 0; j < 10; ++j) {
        accP[j].x += __shfl_xor(accP[j].x, 16, 64); accP[j].x += __shfl_xor(accP[j].x, 32, 64);
        accP[j].y += __shfl_xor(accP[j].y, 16, 64); accP[j].y += __shfl_xor(accP[j].y, 32, 64);
        accM[j].x += __shfl_xor(accM[j].x, 16, 64); accM[j].x += __shfl_xor(accM[j].x, 32, 64);
        accM[j].y += __shfl_xor(accM[j].y, 16, 64); accM[j].y += __shfl_xor(accM[j].y, 32, 64);
    }
    if (lane < 16) {
        const float GP[10] = {1.0f, 0.60653066f, 0.13533528f, 0.011108997f,
                              3.3546263e-4f, 3.7266532e-6f, 1.5229979e-8f,
                              2.2897348e-11f, 1.2664166e-14f, 2.5767430e-18f};
        const float GM[10] = {0.60653066f, 0.13533528f, 0.011108997f,
                              3.3546263e-4f, 3.7266532e-6f, 1.5229979e-8f,
                              2.2897348e-11f, 1.2664166e-14f, 2.5767430e-18f,
                              1.9287498e-22f};
        #pragma unroll
        for (int j = 0; j < 10; ++j) {
            SSh[w][l15][10 + j]      = accP[j].x * GP[j];
            SSh[w][l15][9 - j]       = accM[j].x * GM[j];
            SSh[w][l15 + 16][10 + j] = accP[j].y * GP[j];
            SSh[w][l15 + 16][9 - j]  = accM[j].y * GM[j];
        }
    }
    __syncthreads();

    // ---- log1p over [q][k]
    for (int idx = tid; idx < LQ * NK; idx += 256) {
        int q = idx / NK, k = idx - q * NK;
        float s;
        if (k == 20) {
            s = SSe[0][q] + SSe[1][q] + SSe[2][q] + SSe[3][q]
              + SSe[4][q] + SSe[5][q] + SSe[6][q] + SSe[7][q];
        } else {
            s = SSh[0][q][k] + SSh[1][q][k] + SSh[2][q][k] + SSh[3][q][k];
        }
        Lbuf[idx] = log1pf(s);
    }
    __syncthreads();

    // ---- pool over q -> 21 features
    if (tid < NK) {
        float s = 0.0f;
        #pragma unroll 1
        for (int q = 0; q < LQ; ++q) s += Lbuf[q * NK + tid];
        xk[tid] = s;
    }
    __syncthreads();

    // ---- MLP 21 -> 10 -> 5 -> 1
    if (tid < 10) {
        float s = b0[tid];
        #pragma unroll
        for (int k = 0; k < NK; ++k) s = fmaf(xk[k], w0[tid * NK + k], s);
        h0s[tid] = fmaxf(s, 0.0f);
    }
    __syncthreads();
    if (tid < 5) {
        float s = b1[tid];
        #pragma unroll
        for (int k = 0; k < 10; ++k) s = fmaf(h0s[k], w1[tid * 10 + k], s);
        h1s[tid] = fmaxf(s, 0.0f);
    }
    __syncthreads();
    if (tid == 0) {
        float s = b2[0];
        #pragma unroll
        for (int k = 0; k < 5; ++k) s = fmaf(h1s[k], w2[k], s);
        logits[bid] = s;
    }
}

__global__ void knrm_fin(const float* __restrict__ lg, float* __restrict__ out) {
    int i = blockIdx.x * 256 + threadIdx.x;
    if (i < 1024) {
        float z = lg[2 * i] - lg[2 * i + 1];
        out[i] = 1.0f / (1.0f + __expf(-z));
    }
}

extern "C" void kernel_launch(void* const* d_in, const int* in_sizes, int n_in,
                              void* d_out, int out_size, void* d_ws, size_t ws_size,
                              hipStream_t stream) {
    const float* emb = (const float*)d_in[0];
    const float* w0  = (const float*)d_in[1];
    const float* b0  = (const float*)d_in[2];
    const float* w1  = (const float*)d_in[3];
    const float* b1  = (const float*)d_in[4];
    const float* w2  = (const float*)d_in[5];
    const float* b2  = (const float*)d_in[6];
    const int*   q1  = (const int*)d_in[7];
    const int*   d1  = (const int*)d_in[8];
    const int*   q2  = (const int*)d_in[9];
    const int*   d2  = (const int*)d_in[10];
    float* out = (float*)d_out;

    unsigned* emb16 = (unsigned*)d_ws;                        // 12.8 MB
    float* logits   = (float*)((char*)d_ws + 12800000);       // +8 KB

    knrm_prep<<<(VOCAB + 3) / 4, 256, 0, stream>>>(emb, emb16);
    knrm_main<<<2048, 256, 0, stream>>>((const unsigned short*)emb16,
                                        w0, b0, w1, b1, w2, b2,
                                        q1, d1, q2, d2, logits);
    knrm_fin<<<4, 256, 0, stream>>>(logits, out);
}